// Round 1
// baseline (670.174 us; speedup 1.0000x reference)
//
#include <hip/hip_runtime.h>

typedef unsigned short ushort_t;
typedef __attribute__((ext_vector_type(8))) short bf16x8;
typedef __attribute__((ext_vector_type(4))) float f32x4;

#define DEV static __device__ __forceinline__

DEV ushort_t f2bf(float f){
  union { float f; unsigned u; } v; v.f = f;
  unsigned r = v.u + 0x7FFFu + ((v.u >> 16) & 1u);
  return (ushort_t)(r >> 16);
}
DEV float bf2f(ushort_t h){
  union { unsigned u; float f; } v; v.u = ((unsigned)h) << 16;
  return v.f;
}
DEV float gelu_f(float x){ return 0.5f * x * (1.f + erff(x * 0.70710678118654752f)); }

#define MFMA16(a,b,c) __builtin_amdgcn_mfma_f32_16x16x32_bf16((a),(b),(c),0,0,0)

// ---------------- weight prep ----------------

// dst[n][k] = (bf16)src[k][n]; K,N multiples of 32
__global__ __launch_bounds__(256) void transpose_cast_kernel(
    const float* __restrict__ src, ushort_t* __restrict__ dst, int K, int N){
  __shared__ float tile[32][33];
  int k0 = blockIdx.x * 32, n0 = blockIdx.y * 32;
  int tx = threadIdx.x & 31, ty = threadIdx.x >> 5;
  #pragma unroll
  for(int i = ty; i < 32; i += 8) tile[i][tx] = src[(long)(k0+i)*N + n0 + tx];
  __syncthreads();
  #pragma unroll
  for(int i = ty; i < 32; i += 8) dst[(long)(n0+i)*K + k0 + tx] = f2bf(tile[tx][i]);
}

__global__ void cast_kernel(const float* __restrict__ src, ushort_t* __restrict__ dst, int n){
  int i = blockIdx.x*256 + threadIdx.x;
  if(i < n) dst[i] = f2bf(src[i]);
}

// conv2_w (co,ci,3,3) -> dst[co][(dy,dx,ci)] bf16
__global__ void conv2_reorder_kernel(const float* __restrict__ src, ushort_t* __restrict__ dst){
  int i = blockIdx.x*256 + threadIdx.x;
  if(i >= 384*3456) return;
  int co = i / 3456, r = i - co*3456;
  int dy = r / 1152; int r2 = r - dy*1152;
  int dx = r2 / 384; int ci = r2 - dx*384;
  dst[i] = f2bf(src[((co*384 + ci)*3 + dy)*3 + dx]);
}

// ---------------- LayerNorm (row over last dim) ----------------
// one wave per row; block = 4 rows
template<int D, bool GELU, bool RES>
__global__ __launch_bounds__(256) void ln_kernel(
    const float* __restrict__ in, const float* __restrict__ w, const float* __restrict__ bv,
    const float* __restrict__ res, float eps,
    ushort_t* __restrict__ outb, float* __restrict__ outf){
  constexpr int PER = D/64;
  int lane = threadIdx.x & 63, wid = threadIdx.x >> 6;
  long row = (long)blockIdx.x*4 + wid;
  const float* ip = in + row*D;
  float x[PER]; float s = 0.f;
  #pragma unroll
  for(int i=0;i<PER;i++){ x[i] = ip[i*64 + lane]; s += x[i]; }
  #pragma unroll
  for(int o=32;o>=1;o>>=1) s += __shfl_xor(s, o);
  float mu = s * (1.f/D);
  float vs = 0.f;
  #pragma unroll
  for(int i=0;i<PER;i++){ float d = x[i]-mu; vs += d*d; }
  #pragma unroll
  for(int o=32;o>=1;o>>=1) vs += __shfl_xor(vs, o);
  float rstd = rsqrtf(vs*(1.f/D) + eps);
  #pragma unroll
  for(int i=0;i<PER;i++){
    int c = i*64 + lane;
    float y = (x[i]-mu)*rstd*w[c] + bv[c];
    if constexpr(GELU) y = gelu_f(y);
    if constexpr(RES)  y += res[row*D + c];
    if(outb) outb[row*D + c] = f2bf(y);
    if(outf) outf[row*D + c] = y;
  }
}

// ---------------- decomposed rel-pos bias tables ----------------
// relh[(bh*2304+n)*48 + kk] = sum_d q[bh][n][d] * rel_pos_h[qh-kk+47][d]   (y=0)
// relw ... with qw, rel_pos_w                                              (y=1)
__global__ __launch_bounds__(256) void relpos_kernel(
    const ushort_t* __restrict__ q, const float* __restrict__ rph, const float* __restrict__ rpw,
    float* __restrict__ relh, float* __restrict__ relw){
  int i = blockIdx.x*256 + threadIdx.x;       // (bh*2304+n)*48 + kk
  int kk = i % 48; int bn = i / 48;
  int n = bn % 2304;
  int qh = n / 48, qw = n - qh*48;
  bool isH = (blockIdx.y == 0);
  int dpos = (isH ? qh : qw) - kk + 47;
  const float* tab = (isH ? rph : rpw) + (long)dpos*64;
  const ushort_t* qrow = q + (long)bn*64;
  float s = 0.f;
  #pragma unroll
  for(int jj=0;jj<8;jj++){
    bf16x8 qv = *(const bf16x8*)(qrow + jj*8);
    #pragma unroll
    for(int j=0;j<8;j++) s += bf2f((ushort_t)qv[j]) * tab[jj*8 + j];
  }
  (isH ? relh : relw)[i] = s;
}

// ---------------- generic bf16 MFMA GEMM ----------------
// C[m,n] = sum_k A[m,k]*Wt[n,k];  A row-major bf16 [M][K], Wt row-major bf16 [N][K]
// tile 64x64, BK=64, 4 waves (2x2), each wave 32x32.
// EPI: 0=raw f32; 1=QKV scatter (+bias); 2=+bias+res->f32; 3=+bias,GELU->bf16; 4=+bias+res->f32+bf16
template<int EPI, bool IM2COL>
__global__ __launch_bounds__(256) void gemm_kernel(
    const ushort_t* __restrict__ A, const ushort_t* __restrict__ Wt,
    const float* __restrict__ bias, const float* __restrict__ res,
    float* __restrict__ outf, ushort_t* __restrict__ ob0,
    ushort_t* __restrict__ ob1, ushort_t* __restrict__ ob2,
    int N, int Kdim){
  __shared__ __align__(16) ushort_t Asm[64][72];
  __shared__ __align__(16) ushort_t Bsm[64][72];
  int tid = threadIdx.x;
  int lane = tid & 63, w = tid >> 6;
  int wm = w >> 1, wn = w & 1;
  int la = lane & 15, grp = lane >> 4;
  int m0 = blockIdx.y * 64, n0 = blockIdx.x * 64;
  f32x4 acc[2][2];
  #pragma unroll
  for(int i=0;i<2;i++)
    #pragma unroll
    for(int j=0;j<2;j++)
      #pragma unroll
      for(int r=0;r<4;r++) acc[i][j][r] = 0.f;

  int sr = tid >> 3, scs = (tid & 7) * 8;
  for(int k0 = 0; k0 < Kdim; k0 += 64){
    __syncthreads();
    #pragma unroll
    for(int p=0; p<2; p++){
      int r = sr + p*32;
      bf16x8 av;
      if constexpr(IM2COL){
        int mm = m0 + r;
        int kk = k0 + scs;
        int bb = mm / 2304; int rm = mm - bb*2304;
        int y = rm / 48, x0 = rm - y*48;
        int dy = kk / 1152; int r3 = kk - dy*1152;
        int dx = r3 / 384;  int ci = r3 - dx*384;
        int yy = y + dy - 1, xx = x0 + dx - 1;
        #pragma unroll
        for(int z=0;z<8;z++) av[z] = 0;
        if((unsigned)yy < 48u && (unsigned)xx < 48u)
          av = *(const bf16x8*)(A + ((long)((bb*48+yy)*48+xx))*384 + ci);
      } else {
        av = *(const bf16x8*)(A + (long)(m0+r)*Kdim + k0 + scs);
      }
      *(bf16x8*)&Asm[r][scs] = av;
      bf16x8 bvv = *(const bf16x8*)(Wt + (long)(n0+r)*Kdim + k0 + scs);
      *(bf16x8*)&Bsm[r][scs] = bvv;
    }
    __syncthreads();
    #pragma unroll
    for(int ks=0; ks<2; ks++){
      bf16x8 a0 = *(const bf16x8*)&Asm[wm*32 + la][ks*32 + grp*8];
      bf16x8 a1 = *(const bf16x8*)&Asm[wm*32 + 16 + la][ks*32 + grp*8];
      bf16x8 b0 = *(const bf16x8*)&Bsm[wn*32 + la][ks*32 + grp*8];
      bf16x8 b1 = *(const bf16x8*)&Bsm[wn*32 + 16 + la][ks*32 + grp*8];
      acc[0][0] = MFMA16(a0, b0, acc[0][0]);
      acc[0][1] = MFMA16(a0, b1, acc[0][1]);
      acc[1][0] = MFMA16(a1, b0, acc[1][0]);
      acc[1][1] = MFMA16(a1, b1, acc[1][1]);
    }
  }
  #pragma unroll
  for(int mi=0;mi<2;mi++)
  #pragma unroll
  for(int ni=0;ni<2;ni++)
  #pragma unroll
  for(int r=0;r<4;r++){
    int mm = m0 + wm*32 + mi*16 + grp*4 + r;
    int nn = n0 + wn*32 + ni*16 + la;
    float v = acc[mi][ni][r];
    if constexpr(EPI == 0){
      outf[(long)mm*N + nn] = v;
    } else if constexpr(EPI == 1){
      v += bias[nn];
      int s = nn / 768; int rem = nn - s*768;
      int head = rem >> 6, d = rem & 63;
      int bb = mm / 2304; int nloc = mm - bb*2304;
      long idx = ((long)((bb*12+head)*2304 + nloc))*64 + d;
      ushort_t hv = f2bf(v);
      if(s == 0) ob0[idx] = hv; else if(s == 1) ob1[idx] = hv; else ob2[idx] = hv;
    } else if constexpr(EPI == 2){
      v += bias[nn] + res[(long)mm*N + nn];
      outf[(long)mm*N + nn] = v;
    } else if constexpr(EPI == 3){
      v = gelu_f(v + bias[nn]);
      ob0[(long)mm*N + nn] = f2bf(v);
    } else if constexpr(EPI == 4){
      v += bias[nn] + res[(long)mm*N + nn];
      outf[(long)mm*N + nn] = v;
      ob0[(long)mm*N + nn] = f2bf(v);
    }
  }
}

// ---------------- flash attention with rel-pos bias ----------------
// grid (36 q-tiles, 24 bh), 256 threads (4 waves, wave w owns q rows w*16..w*16+15)
__global__ __launch_bounds__(256) void attn_kernel(
    const ushort_t* __restrict__ Q, const ushort_t* __restrict__ Kb,
    const ushort_t* __restrict__ V, const float* __restrict__ relh,
    const float* __restrict__ relw, ushort_t* __restrict__ outp){
  __shared__ __align__(16) float Ssm[64][65];
  __shared__ __align__(16) ushort_t Psm[64][72];
  __shared__ __align__(16) ushort_t Vt[64][72];
  __shared__ float mrow[64], lrow[64], arow[64];
  int bh = blockIdx.y, qt = blockIdx.x;
  int tid = threadIdx.x, lane = tid & 63, w = tid >> 6;
  int la = lane & 15, grp = lane >> 4;
  int b = bh / 12, head = bh - b*12;
  const float scale = 0.125f;

  bf16x8 qa[2];
  {
    const ushort_t* qp = Q + ((long)(bh*2304 + qt*64 + w*16 + la))*64 + grp*8;
    qa[0] = *(const bf16x8*)qp;
    qa[1] = *(const bf16x8*)(qp + 32);
  }
  f32x4 acc[4];
  #pragma unroll
  for(int i=0;i<4;i++){
    #pragma unroll
    for(int r=0;r<4;r++) acc[i][r] = 0.f;
  }
  if(tid < 64){ mrow[tid] = -1e30f; lrow[tid] = 0.f; }

  const float* rh = relh + ((long)(bh*2304 + qt*64))*48;
  const float* rw = relw + ((long)(bh*2304 + qt*64))*48;
  int srow = tid >> 2, q4 = tid & 3, c0 = q4*16;

  for(int kt = 0; kt < 36; kt++){
    __syncthreads();
    // stage V transposed + XOR-swizzled: Vt[d][key ^ ((d>>3)<<3)] = V[key][d]
    #pragma unroll
    for(int p=0;p<2;p++){
      int item = tid + p*256;
      int key = item >> 3, dblk = item & 7;
      bf16x8 vv = *(const bf16x8*)(V + ((long)(bh*2304 + kt*64 + key))*64 + dblk*8);
      int scol = key ^ (dblk << 3);
      #pragma unroll
      for(int j=0;j<8;j++) Vt[dblk*8 + j][scol] = (ushort_t)vv[j];
    }
    // S = Q K^T (raw dot, scale+bias applied later)
    const ushort_t* kbase = Kb + ((long)(bh*2304 + kt*64))*64;
    #pragma unroll
    for(int nf=0; nf<4; nf++){
      f32x4 sacc;
      #pragma unroll
      for(int r=0;r<4;r++) sacc[r] = 0.f;
      const ushort_t* kp = kbase + (nf*16 + la)*64 + grp*8;
      sacc = MFMA16(qa[0], *(const bf16x8*)kp,        sacc);
      sacc = MFMA16(qa[1], *(const bf16x8*)(kp + 32), sacc);
      #pragma unroll
      for(int r=0;r<4;r++) Ssm[w*16 + grp*4 + r][nf*16 + la] = sacc[r];
    }
    __syncthreads();
    // online softmax: thread -> (row = tid>>2, cols c0..c0+15)
    float vals[16]; float lmax = -1e30f;
    const float* rhr = rh + srow*48;
    const float* rwr = rw + srow*48;
    int kb0 = kt*64 + c0;
    #pragma unroll
    for(int j=0;j<16;j++){
      int kc = kb0 + j;
      int kh = kc / 48, kw = kc - kh*48;
      float sv = Ssm[srow][c0+j]*scale + rhr[kh] + rwr[kw];
      vals[j] = sv;
      lmax = fmaxf(lmax, sv);
    }
    lmax = fmaxf(lmax, __shfl_xor(lmax, 1));
    lmax = fmaxf(lmax, __shfl_xor(lmax, 2));
    float mold = mrow[srow];
    float mnew = fmaxf(mold, lmax);
    float psum = 0.f;
    #pragma unroll
    for(int j=0;j<16;j++){
      float p = __expf(vals[j] - mnew);
      Psm[srow][c0+j] = f2bf(p);
      psum += p;
    }
    psum += __shfl_xor(psum, 1);
    psum += __shfl_xor(psum, 2);
    if(q4 == 0){
      float alpha = __expf(mold - mnew);
      arow[srow] = alpha;
      lrow[srow] = lrow[srow]*alpha + psum;
      mrow[srow] = mnew;
    }
    __syncthreads();
    // rescale O, then O += P V
    float al[4];
    #pragma unroll
    for(int r=0;r<4;r++) al[r] = arow[w*16 + grp*4 + r];
    #pragma unroll
    for(int nf=0;nf<4;nf++)
      #pragma unroll
      for(int r=0;r<4;r++) acc[nf][r] *= al[r];
    #pragma unroll
    for(int ks=0; ks<2; ks++){
      bf16x8 pa = *(const bf16x8*)&Psm[w*16 + la][ks*32 + grp*8];
      #pragma unroll
      for(int nf=0; nf<4; nf++){
        int d = nf*16 + la;
        int blk = (ks*4 + grp) ^ (d >> 3);
        bf16x8 vb = *(const bf16x8*)&Vt[d][blk*8];
        acc[nf] = MFMA16(pa, vb, acc[nf]);
      }
    }
  }
  float linv[4];
  #pragma unroll
  for(int r=0;r<4;r++) linv[r] = 1.f / lrow[w*16 + grp*4 + r];
  #pragma unroll
  for(int nf=0; nf<4; nf++)
    #pragma unroll
    for(int r=0;r<4;r++){
      int nq = qt*64 + w*16 + grp*4 + r;
      long t = (long)b*2304 + nq;
      int c = head*64 + nf*16 + la;
      outp[t*768 + c] = f2bf(acc[nf][r] * linv[r]);
    }
}

// ---------------- launch ----------------
extern "C" void kernel_launch(void* const* d_in, const int* in_sizes, int n_in,
                              void* d_out, int out_size, void* d_ws, size_t ws_size,
                              hipStream_t stream){
  const float* x     = (const float*)d_in[0];
  const float* n1w   = (const float*)d_in[1];
  const float* n1b   = (const float*)d_in[2];
  const float* qkvw  = (const float*)d_in[3];
  const float* qkvb  = (const float*)d_in[4];
  const float* projw = (const float*)d_in[5];
  const float* projb = (const float*)d_in[6];
  const float* rph   = (const float*)d_in[7];
  const float* rpw   = (const float*)d_in[8];
  const float* n2w   = (const float*)d_in[9];
  const float* n2b   = (const float*)d_in[10];
  const float* fc1w  = (const float*)d_in[11];
  const float* fc1b  = (const float*)d_in[12];
  const float* fc2w  = (const float*)d_in[13];
  const float* fc2b  = (const float*)d_in[14];
  const float* c1w   = (const float*)d_in[15];
  const float* r1w   = (const float*)d_in[16];
  const float* r1b   = (const float*)d_in[17];
  const float* c2w   = (const float*)d_in[18];
  const float* r2w   = (const float*)d_in[19];
  const float* r2b   = (const float*)d_in[20];
  const float* c3w   = (const float*)d_in[21];
  const float* r3w   = (const float*)d_in[22];
  const float* r3b   = (const float*)d_in[23];
  float* out = (float*)d_out;

  char* base = (char*)d_ws;
  size_t off = 0;
  auto carve = [&](size_t bytes)->char*{
    char* p = base + off;
    off += (bytes + 255) & ~(size_t)255;
    return p;
  };
  const long T = 4608;

  ushort_t* wqkvT = (ushort_t*)carve((size_t)2304*768*2);
  ushort_t* wprojT= (ushort_t*)carve((size_t)768*768*2);
  ushort_t* wfc1T = (ushort_t*)carve((size_t)3072*768*2);
  ushort_t* wfc2T = (ushort_t*)carve((size_t)768*3072*2);
  ushort_t* wc1   = (ushort_t*)carve((size_t)384*768*2);
  ushort_t* wc2   = (ushort_t*)carve((size_t)384*3456*2);
  ushort_t* wc3   = (ushort_t*)carve((size_t)768*384*2);
  ushort_t* xn1   = (ushort_t*)carve((size_t)T*768*2);
  ushort_t* qb    = (ushort_t*)carve((size_t)24*2304*64*2);
  ushort_t* kbuf  = (ushort_t*)carve((size_t)24*2304*64*2);
  ushort_t* vbuf  = (ushort_t*)carve((size_t)24*2304*64*2);
  float*    relh  = (float*)carve((size_t)24*2304*48*4);
  float*    relw  = (float*)carve((size_t)24*2304*48*4);
  ushort_t* attno = (ushort_t*)carve((size_t)T*768*2);
  float*    x1    = (float*)carve((size_t)T*768*4);
  ushort_t* xn2   = (ushort_t*)carve((size_t)T*768*2);
  ushort_t* hmlp  = (ushort_t*)carve((size_t)T*3072*2);
  float*    x2    = (float*)carve((size_t)T*768*4);
  ushort_t* x2b   = (ushort_t*)carve((size_t)T*768*2);
  float*    c1    = (float*)carve((size_t)T*384*4);
  ushort_t* o1    = (ushort_t*)carve((size_t)T*384*2);
  float*    c2    = (float*)carve((size_t)T*384*4);
  ushort_t* o2    = (ushort_t*)carve((size_t)T*384*2);
  float*    c3    = (float*)carve((size_t)T*768*4);
  (void)ws_size; (void)in_sizes; (void)n_in; (void)out_size;

  // weight prep
  transpose_cast_kernel<<<dim3(24,72),256,0,stream>>>(qkvw, wqkvT, 768, 2304);
  transpose_cast_kernel<<<dim3(24,24),256,0,stream>>>(projw, wprojT, 768, 768);
  transpose_cast_kernel<<<dim3(24,96),256,0,stream>>>(fc1w, wfc1T, 768, 3072);
  transpose_cast_kernel<<<dim3(96,24),256,0,stream>>>(fc2w, wfc2T, 3072, 768);
  cast_kernel<<<dim3(1152),256,0,stream>>>(c1w, wc1, 384*768);
  conv2_reorder_kernel<<<dim3(5184),256,0,stream>>>(c2w, wc2);
  cast_kernel<<<dim3(1152),256,0,stream>>>(c3w, wc3, 768*384);

  // LN1
  ln_kernel<768,false,false><<<dim3(1152),256,0,stream>>>(x, n1w, n1b, nullptr, 1e-5f, xn1, nullptr);
  // QKV + scatter
  gemm_kernel<1,false><<<dim3(36,72),256,0,stream>>>(xn1, wqkvT, qkvb, nullptr, nullptr, qb, kbuf, vbuf, 2304, 768);
  // rel-pos bias tables
  relpos_kernel<<<dim3(10368,2),256,0,stream>>>(qb, rph, rpw, relh, relw);
  // flash attention
  attn_kernel<<<dim3(36,24),256,0,stream>>>(qb, kbuf, vbuf, relh, relw, attno);
  // proj + residual(x)
  gemm_kernel<2,false><<<dim3(12,72),256,0,stream>>>(attno, wprojT, projb, x, x1, nullptr, nullptr, nullptr, 768, 768);
  // LN2
  ln_kernel<768,false,false><<<dim3(1152),256,0,stream>>>(x1, n2w, n2b, nullptr, 1e-5f, xn2, nullptr);
  // fc1 + GELU
  gemm_kernel<3,false><<<dim3(48,72),256,0,stream>>>(xn2, wfc1T, fc1b, nullptr, nullptr, hmlp, nullptr, nullptr, 3072, 768);
  // fc2 + residual(x1) -> x2 (f32+bf16)
  gemm_kernel<4,false><<<dim3(12,72),256,0,stream>>>(hmlp, wfc2T, fc2b, x1, x2, x2b, nullptr, nullptr, 768, 3072);
  // conv1 (1x1)
  gemm_kernel<0,false><<<dim3(6,72),256,0,stream>>>(x2b, wc1, nullptr, nullptr, c1, nullptr, nullptr, nullptr, 384, 768);
  ln_kernel<384,true,false><<<dim3(1152),256,0,stream>>>(c1, r1w, r1b, nullptr, 1e-6f, o1, nullptr);
  // conv2 (3x3 via im2col)
  gemm_kernel<0,true><<<dim3(6,72),256,0,stream>>>(o1, wc2, nullptr, nullptr, c2, nullptr, nullptr, nullptr, 384, 3456);
  ln_kernel<384,true,false><<<dim3(1152),256,0,stream>>>(c2, r2w, r2b, nullptr, 1e-6f, o2, nullptr);
  // conv3 (1x1)
  gemm_kernel<0,false><<<dim3(12,72),256,0,stream>>>(o2, wc3, nullptr, nullptr, c3, nullptr, nullptr, nullptr, 768, 384);
  // final chan-LN + residual(x2) -> out
  ln_kernel<768,false,true><<<dim3(1152),256,0,stream>>>(c3, r3w, r3b, x2, 1e-6f, nullptr, out);
}